// Round 1
// 557.565 us; speedup vs baseline: 1.0789x; 1.0789x over previous
//
#include <hip/hip_runtime.h>

typedef __bf16 bf16;
typedef __bf16 bf16x8 __attribute__((ext_vector_type(8)));
typedef float  f32x4  __attribute__((ext_vector_type(4)));

// Problem constants: B=32, N_PIC=4, C=3, H=W=224, P=16, HP=14, NP=196, D=768

// ---------------------------------------------------------------------------
// patchify + cast to bf16: x[128,3,224,224] f32 -> p[128*196, 768] bf16
__global__ __launch_bounds__(256) void patchify_k(const float* __restrict__ x,
                                                  bf16* __restrict__ p) {
  int t = blockIdx.x * 256 + threadIdx.x;
  if (t >= 128 * 3 * 14 * 16 * 14) return;
  int j  = t % 14; t /= 14;
  int ph = t % 16; t /= 16;
  int i  = t % 14; t /= 14;
  int c  = t % 3;  t /= 3;
  int bn = t;
  const float* src = x + (((long long)(bn * 3 + c) * 224 + (i * 16 + ph)) * 224 + j * 16);
  bf16* dst = p + ((long long)(bn * 196 + (i * 14 + j)) * 768 + c * 256 + ph * 16);
  bf16 tmp[16];
  for (int k = 0; k < 16; k += 4) {
    float4 f = *(const float4*)(src + k);
    tmp[k + 0] = (bf16)f.x; tmp[k + 1] = (bf16)f.y;
    tmp[k + 2] = (bf16)f.z; tmp[k + 3] = (bf16)f.w;
  }
  *(bf16x8*)(dst)     = *(bf16x8*)&tmp[0];
  *(bf16x8*)(dst + 8) = *(bf16x8*)&tmp[8];
}

// ---------------------------------------------------------------------------
// transpose + cast the 6 weights: W[k][n] f32 (768x768) -> Wt[n][k] bf16
// call order (W1, Wk, Wv, Wq, Wo1, Wo2) => wt+WSZ is the fused 1536-row KV wt.
__global__ __launch_bounds__(256) void wtrans_k(const float* __restrict__ w0,
                                                const float* __restrict__ w1,
                                                const float* __restrict__ w2,
                                                const float* __restrict__ w3,
                                                const float* __restrict__ w4,
                                                const float* __restrict__ w5,
                                                bf16* __restrict__ out) {
  __shared__ float tile[32][33];
  const float* W;
  switch (blockIdx.z) {
    case 0: W = w0; break; case 1: W = w1; break; case 2: W = w2; break;
    case 3: W = w3; break; case 4: W = w4; break; default: W = w5; break;
  }
  bf16* o = out + (long long)blockIdx.z * 768 * 768;
  int nb = blockIdx.x * 32, kb = blockIdx.y * 32;
  int c = threadIdx.x & 31, r = threadIdx.x >> 5;
  for (int rr = 0; rr < 32; rr += 8)
    tile[r + rr][c] = W[(long long)(kb + r + rr) * 768 + nb + c];
  __syncthreads();
  for (int rr = 0; rr < 32; rr += 8)
    o[(long long)(nb + r + rr) * 768 + kb + c] = (bf16)tile[c][r + rr];
}

// ---------------------------------------------------------------------------
// transpose V out of fused kv[z][196][1536] (V = cols 768..1535)
// -> Vt[z][768][224] bf16, zero-padding m in [196,224)
__global__ __launch_bounds__(256) void vtrans_k(const bf16* __restrict__ kv,
                                                bf16* __restrict__ Vt) {
  __shared__ short tile[32][33];
  int z = blockIdx.z;
  const short* v = (const short*)(kv + (long long)z * 301056 + 768);
  short* vt = (short*)(Vt + (long long)z * 768 * 224);
  int db = blockIdx.x * 32;
  int mb = blockIdx.y * 32;
  int c = threadIdx.x & 31, r = threadIdx.x >> 5;
  for (int rr = 0; rr < 32; rr += 8) {
    int m = mb + r + rr;
    short val = 0;
    if (m < 196) val = v[(long long)m * 1536 + db + c];
    tile[r + rr][c] = val;
  }
  __syncthreads();
  for (int rr = 0; rr < 32; rr += 8) {
    int d = db + r + rr;
    vt[(long long)d * 224 + mb + c] = tile[c][r + rr];
  }
}

// ---------------------------------------------------------------------------
// softmax over rows of 196 f32 scores -> bf16 attn rows padded to 224
__global__ __launch_bounds__(64) void softmax_k(const float* __restrict__ S,
                                                bf16* __restrict__ attn) {
  const int row = blockIdx.x;
  const float* sr = S + (long long)row * 196;
  const int l = threadIdx.x;
  float v0 = sr[l];
  float v1 = sr[l + 64];
  float v2 = sr[l + 128];
  float v3 = (l + 192 < 196) ? sr[l + 192] : -1e30f;
  float mx = fmaxf(fmaxf(v0, v1), fmaxf(v2, v3));
  for (int o = 32; o > 0; o >>= 1) mx = fmaxf(mx, __shfl_xor(mx, o));
  float e0 = __expf(v0 - mx);
  float e1 = __expf(v1 - mx);
  float e2 = __expf(v2 - mx);
  float e3 = (l + 192 < 196) ? __expf(v3 - mx) : 0.f;
  float s = e0 + e1 + e2 + e3;
  for (int o = 32; o > 0; o >>= 1) s += __shfl_xor(s, o);
  float inv = 1.0f / s;
  bf16* ar = attn + (long long)row * 224;
  ar[l]       = (bf16)(e0 * inv);
  ar[l + 64]  = (bf16)(e1 * inv);
  ar[l + 128] = (bf16)(e2 * inv);
  int m3 = l + 192;
  if (m3 < 196) ar[m3] = (bf16)(e3 * inv);
  else if (m3 < 224) ar[m3] = (bf16)0.0f;
}

// ---------------------------------------------------------------------------
__device__ __forceinline__ void gld16(const bf16* g, bf16* l) {
  __builtin_amdgcn_global_load_lds(
      (const __attribute__((address_space(1))) unsigned int*)g,
      (__attribute__((address_space(3))) unsigned int*)l, 16, 0, 0);
}

// Pipelined bf16 MFMA GEMM: 128x128 tile, BK=32, double-buffered LDS.
// (retained for q / scores / wv — shapes not divisible by 256 or K%64!=0)
__global__ __launch_bounds__(256) void gemm128(
    const bf16* __restrict__ A, const bf16* __restrict__ Bt,
    const float* __restrict__ bias, const float* __restrict__ bias2,
    void* __restrict__ Cout,
    int M, int N, int K, int lda, int ldb, int gr, long long gs,
    long long strideAz, int a_zdiv, long long strideBz, long long strideCz,
    float scale, int relu, int out_bf16) {
  __shared__ __align__(16) char smem[34816];
  bf16* AsBuf = (bf16*)smem;              // [2][4096]
  bf16* BsBuf = (bf16*)(smem + 16384);    // [2][4096]

  const int tid = threadIdx.x;
  const int lane = tid & 63;
  const int w = tid >> 6;
  const int wm = w & 1, wn = w >> 1;
  const int z = blockIdx.z;
  const int n0 = blockIdx.x * 128, m0 = blockIdx.y * 128;

  const bf16* Az  = A  + (long long)(z / a_zdiv) * strideAz;
  const bf16* Btz = Bt + (long long)z * strideBz;

  const int rl  = 16 * w + (lane & 15);       // 0..63
  const int kc8 = (lane >> 4) * 8;            // 0,8,16,24
  int ar0 = m0 + rl;        if (ar0 >= M) ar0 = M - 1;
  int ar1 = m0 + 64 + rl;   if (ar1 >= M) ar1 = M - 1;
  const bf16* aP0 = Az + (long long)(ar0 / gr) * gs + (long long)(ar0 % gr) * lda + kc8;
  const bf16* aP1 = Az + (long long)(ar1 / gr) * gs + (long long)(ar1 % gr) * lda + kc8;
  int br0 = n0 + rl;        if (br0 >= N) br0 = N - 1;
  int br1 = n0 + 64 + rl;   if (br1 >= N) br1 = N - 1;
  const bf16* bP0 = Btz + (long long)br0 * ldb + kc8;
  const bf16* bP1 = Btz + (long long)br1 * ldb + kc8;

  const int dstOff = w * 512;

#define ISSUE(t, buf) do { const int _o = (t) << 5;                 \
    gld16(aP0 + _o, AsBuf + (buf) * 4096 + dstOff);                 \
    gld16(aP1 + _o, AsBuf + (buf) * 4096 + 2048 + dstOff);          \
    gld16(bP0 + _o, BsBuf + (buf) * 4096 + dstOff);                 \
    gld16(bP1 + _o, BsBuf + (buf) * 4096 + 2048 + dstOff); } while (0)

  const int niter = K >> 5;
  f32x4 acc[4][4] = {};
  const int fr = lane & 15, fq = lane >> 4;

  ISSUE(0, 0);

  for (int i = 0; i < niter; ++i) {
    __syncthreads();
    const int cur = i & 1;
    if (i + 1 < niter) ISSUE(i + 1, cur ^ 1);

    const bf16* Ac = AsBuf + cur * 4096;
    const bf16* Bc = BsBuf + cur * 4096;
    bf16x8 a[4], b[4];
#pragma unroll
    for (int mi = 0; mi < 4; mi++)
      a[mi] = *(const bf16x8*)&Ac[(wm * 4 + mi) * 512 + fq * 128 + fr * 8];
#pragma unroll
    for (int ni = 0; ni < 4; ni++)
      b[ni] = *(const bf16x8*)&Bc[(wn * 4 + ni) * 512 + fq * 128 + fr * 8];
#pragma unroll
    for (int mi = 0; mi < 4; mi++)
#pragma unroll
      for (int ni = 0; ni < 4; ni++)
        acc[mi][ni] = __builtin_amdgcn_mfma_f32_16x16x32_bf16(a[mi], b[ni], acc[mi][ni], 0, 0, 0);
  }
#undef ISSUE

  __syncthreads();

  const long long cz = (long long)z * strideCz;
  if (out_bf16) {
    bf16* Cs = (bf16*)smem;   // [128][136]
#pragma unroll
    for (int ni = 0; ni < 4; ni++) {
      int col = wn * 64 + ni * 16 + fr;
      int gcol = n0 + col;
      float bb = 0.f;
      if (bias) bb = (bias2 && gcol >= 768) ? bias2[gcol - 768] : bias[gcol];
#pragma unroll
      for (int mi = 0; mi < 4; mi++) {
        int rbase = wm * 64 + mi * 16 + fq * 4;
#pragma unroll
        for (int r = 0; r < 4; r++) {
          float v = acc[mi][ni][r] * scale + bb;
          if (relu) v = fmaxf(v, 0.f);
          Cs[(rbase + r) * 136 + col] = (bf16)v;
        }
      }
    }
    __syncthreads();
    bf16* Cp = (bf16*)Cout;
    const int rr = tid >> 4, cc = (tid & 15) * 8;
#pragma unroll
    for (int pp = 0; pp < 8; pp++) {
      int row = pp * 16 + rr;
      int grow = m0 + row;
      if (grow < M)
        *(bf16x8*)(Cp + cz + (long long)grow * N + n0 + cc) =
            *(const bf16x8*)&Cs[row * 136 + cc];
    }
  } else {
    float* Cs = (float*)smem;
    float* Cp = (float*)Cout;
    for (int half = 0; half < 2; ++half) {
      if (wm == half) {
#pragma unroll
        for (int ni = 0; ni < 4; ni++) {
          int col = wn * 64 + ni * 16 + fr;
          int gcol = n0 + col;
          float bb = 0.f;
          if (bias && gcol < N)
            bb = (bias2 && gcol >= 768) ? bias2[gcol - 768] : bias[gcol];
#pragma unroll
          for (int mi = 0; mi < 4; mi++) {
            int rbase = mi * 16 + fq * 4;
#pragma unroll
            for (int r = 0; r < 4; r++) {
              float v = acc[mi][ni][r] * scale + bb;
              if (relu) v = fmaxf(v, 0.f);
              Cs[(rbase + r) * 132 + col] = v;
            }
          }
        }
      }
      __syncthreads();
      const int rr = tid >> 5, cc = (tid & 31) * 4;
#pragma unroll
      for (int pp = 0; pp < 8; pp++) {
        int row = pp * 8 + rr;
        int grow = m0 + half * 64 + row;
        if (grow < M) {
          int gcol = n0 + cc;
          float* dst = Cp + cz + (long long)grow * N + gcol;
          const float* srcl = &Cs[row * 132 + cc];
          if (gcol + 4 <= N) {
            *(float4*)dst = *(const float4*)srcl;
          } else {
            for (int e = 0; e < 4; e++)
              if (gcol + e < N) dst[e] = srcl[e];
          }
        }
      }
      __syncthreads();
    }
  }
}

// ---------------------------------------------------------------------------
// 8-phase 256x256 bf16 MFMA GEMM (plain-HIP port of the HK/cdna4 schedule).
// Requirements: M % 256 == 0, N % 256 == 0, K % 64 == 0, K >= 128.
// 8 waves (2M x 4N), per-wave output 128x64, BK=64, 128 KiB LDS dbuf.
// LDS tile layout: per half-tile (128 rows x 64 cols bf16, 16 KiB):
//   [rowgrp 0..7][colgrp 0..1][prow 0..15][pcol 0..31], with st_16x32 swizzle
//   pcol ^= ((prow&8)?16:0). global_load_lds writes linearly, so the swizzle
//   is applied by permuting the per-lane GLOBAL source address (m173 pattern)
//   and the ds_read address; both use the same involution.
// Stage schedule (1 half-tile per phase, hazard-safe vs region last-reads):
//   p0: A_hi(t+1)  p1: B_hi(t+1)  p2: B_lo(t+2)  p3: A_lo(t+2)
// vmcnt(4) once per K-tile (2 stages = 4 loads allowed outstanding);
// vmcnt(0) at tile nt-2 to drain the final prefetches.
__global__ __launch_bounds__(512, 2) void gemm256(
    const bf16* __restrict__ A, const bf16* __restrict__ Bt,
    const float* __restrict__ bias, const float* __restrict__ bias2,
    void* __restrict__ Cout,
    int N, int K, int lda, int ldb, int relu, int out_bf16) {
  __shared__ __align__(16) char smem[131072];
  bf16* As = (bf16*)smem;            // [2][2][8192] elements
  bf16* Bs = (bf16*)(smem + 65536);

  const int tid = threadIdx.x;
  const int lane = tid & 63;
  const int w = tid >> 6;          // 0..7
  const int wm = w >> 2;           // 0..1  (M half, also A LDS half)
  const int wn = w & 3;            // 0..3

  // bijective XCD-aware block swizzle (m204): contiguous flat-id chunks/XCD
  const int nx = N >> 8;
  const int nwg = gridDim.x * gridDim.y;
  int f = blockIdx.y * gridDim.x + blockIdx.x;
  {
    const int q = nwg >> 3, r = nwg & 7;
    const int xcd = f & 7, idx = f >> 3;
    f = (xcd < r ? xcd * (q + 1) : r * (q + 1) + (xcd - r) * q) + idx;
  }
  const int n0 = (f % nx) * 256;
  const int m0 = (f / nx) * 256;

  // ---- staging source mapping (inverse-swizzled global address) ----
  // physical LDS byte of thread t, issue i = i*8192 + t*16 (per half-tile)
  const int srow = ((tid >> 2) & 15) + ((tid >> 7) << 4);              // 0..63 (i adds 64)
  const int scol = ((tid >> 6) & 1) * 32 +
                   (((tid & 3) << 3) ^ ((tid & 32) ? 16 : 0));
  const bf16* aBase = A  + (long long)(m0 + srow) * lda + scol;
  const bf16* bBase = Bt + (long long)(n0 + srow) * ldb + scol;
  const int ldsw = w * 512;        // wave-uniform LDS window (elements)

#define STG(base, ld, dstArr, buf, kt, hh) do {                              \
    const bf16* _s = (base) + (long long)((hh) * 128) * (ld) + (kt) * 64;    \
    gld16(_s,               (dstArr) + (buf) * 16384 + (hh) * 8192 + ldsw);  \
    gld16(_s + 64LL * (ld), (dstArr) + (buf) * 16384 + (hh) * 8192 + 4096 + ldsw); \
  } while (0)

  // ---- fragment ds_read addressing (swizzled) ----
  const int fr = lane & 15, fq = lane >> 4;
  const int frij = fr * 32 + ((fq * 8) ^ ((fr & 8) ? 16 : 0));
  const bf16* aRd = As + wm * 8192 + frij;                 // + buf*16384 + mi*1024 + kk*512
  const bf16* bRd = Bs + (wn >> 1) * 8192 + (wn & 1) * 4096 + frij;

  f32x4 acc[8][4] = {};
  bf16x8 aF[4][2], bF[4][2];

  const int nt = K >> 6;           // K-tiles of 64

  // ---- prologue: tile0 (4 halves) + B_lo(1), A_lo(1) ----
  STG(aBase, lda, As, 0, 0, 0);
  STG(aBase, lda, As, 0, 0, 1);
  STG(bBase, ldb, Bs, 0, 0, 0);
  STG(bBase, ldb, Bs, 0, 0, 1);
  STG(bBase, ldb, Bs, 1, 1, 0);
  STG(aBase, lda, As, 1, 1, 0);
  asm volatile("s_waitcnt vmcnt(4)" ::: "memory");  // tile0 fully resident
  asm volatile("s_barrier" ::: "memory");

  for (int t = 0; t < nt; ++t) {
    const int buf = t & 1;
    const int bOff = buf << 14;    // *16384 elements

    // ---------------- phase 0: quadrant (m-lo, n-lo) ----------------
#pragma unroll
    for (int mi = 0; mi < 4; ++mi)
#pragma unroll
      for (int kk = 0; kk < 2; ++kk)
        aF[mi][kk] = *(const bf16x8*)(aRd + bOff + mi * 1024 + kk * 512);
#pragma unroll
    for (int ni = 0; ni < 2; ++ni)
#pragma unroll
      for (int kk = 0; kk < 2; ++kk)
        bF[ni][kk] = *(const bf16x8*)(bRd + bOff + ni * 1024 + kk * 512);
    if (t + 1 < nt) STG(aBase, lda, As, buf ^ 1, t + 1, 1);   // A_hi(t+1)
    asm volatile("s_barrier" ::: "memory");
    __builtin_amdgcn_s_setprio(1);
#pragma unroll
    for (int mi = 0; mi < 4; ++mi)
#pragma unroll
      for (int ni = 0; ni < 2; ++ni)
#pragma unroll
        for (int kk = 0; kk < 2; ++kk)
          acc[mi][ni] = __builtin_amdgcn_mfma_f32_16x16x32_bf16(
              aF[mi][kk], bF[ni][kk], acc[mi][ni], 0, 0, 0);
    __builtin_amdgcn_s_setprio(0);
    asm volatile("s_barrier" ::: "memory");

    // ---------------- phase 1: quadrant (m-lo, n-hi) ----------------
#pragma unroll
    for (int ni = 2; ni < 4; ++ni)
#pragma unroll
      for (int kk = 0; kk < 2; ++kk)
        bF[ni][kk] = *(const bf16x8*)(bRd + bOff + ni * 1024 + kk * 512);
    if (t + 1 < nt) STG(bBase, ldb, Bs, buf ^ 1, t + 1, 1);   // B_hi(t+1)
    asm volatile("s_barrier" ::: "memory");
    __builtin_amdgcn_s_setprio(1);
#pragma unroll
    for (int mi = 0; mi < 4; ++mi)
#pragma unroll
      for (int ni = 2; ni < 4; ++ni)
#pragma unroll
        for (int kk = 0; kk < 2; ++kk)
          acc[mi][ni] = __builtin_amdgcn_mfma_f32_16x16x32_bf16(
              aF[mi][kk], bF[ni][kk], acc[mi][ni], 0, 0, 0);
    __builtin_amdgcn_s_setprio(0);
    asm volatile("s_barrier" ::: "memory");

    // ---------------- phase 2: quadrant (m-hi, n-lo) ----------------
#pragma unroll
    for (int mi = 0; mi < 4; ++mi)
#pragma unroll
      for (int kk = 0; kk < 2; ++kk)
        aF[mi][kk] = *(const bf16x8*)(aRd + bOff + (4 + mi) * 1024 + kk * 512);
    if (t + 2 < nt) STG(bBase, ldb, Bs, buf, t + 2, 0);       // B_lo(t+2)
    asm volatile("s_barrier" ::: "memory");
    __builtin_amdgcn_s_setprio(1);
#pragma unroll
    for (int mi = 0; mi < 4; ++mi)
#pragma unroll
      for (int ni = 0; ni < 2; ++ni)
#pragma unroll
        for (int kk = 0; kk < 2; ++kk)
          acc[4 + mi][ni] = __builtin_amdgcn_mfma_f32_16x16x32_bf16(
              aF[mi][kk], bF[ni][kk], acc[4 + mi][ni], 0, 0, 0);
    __builtin_amdgcn_s_setprio(0);
    asm volatile("s_barrier" ::: "memory");

    // ---------------- phase 3: quadrant (m-hi, n-hi) ----------------
    if (t + 2 < nt) STG(aBase, lda, As, buf, t + 2, 0);       // A_lo(t+2)
    asm volatile("s_barrier" ::: "memory");
    __builtin_amdgcn_s_setprio(1);
#pragma unroll
    for (int mi = 0; mi < 4; ++mi)
#pragma unroll
      for (int ni = 2; ni < 4; ++ni)
#pragma unroll
        for (int kk = 0; kk < 2; ++kk)
          acc[4 + mi][ni] = __builtin_amdgcn_mfma_f32_16x16x32_bf16(
              aF[mi][kk], bF[ni][kk], acc[4 + mi][ni], 0, 0, 0);
    __builtin_amdgcn_s_setprio(0);
    if (t < nt - 2)       asm volatile("s_waitcnt vmcnt(4)" ::: "memory");
    else if (t == nt - 2) asm volatile("s_waitcnt vmcnt(0)" ::: "memory");
    asm volatile("s_barrier" ::: "memory");
  }
#undef STG

  // ---- epilogue: stage C through LDS for coalesced 512B-row writes ----
  const long long Nll = N;
  if (out_bf16) {
    bf16* Cs = (bf16*)smem;      // [128][268]
    bf16* Cp = (bf16*)Cout;
#pragma unroll
    for (int half = 0; half < 2; ++half) {
      if (wm == half) {
#pragma unroll
        for (int ni = 0; ni < 4; ++ni) {
          const int col = wn * 64 + ni * 16 + fr;
          const int gcol = n0 + col;
          float bb = 0.f;
          if (bias) bb = (bias2 && gcol >= 768) ? bias2[gcol - 768] : bias[gcol];
#pragma unroll
          for (int mi = 0; mi < 8; ++mi) {
#pragma unroll
            for (int r = 0; r < 4; ++r) {
              float v = acc[mi][ni][r] + bb;
              if (relu) v = fmaxf(v, 0.f);
              Cs[(mi * 16 + fq * 4 + r) * 268 + col] = (bf16)v;
            }
          }
        }
      }
      __syncthreads();
      const int row = tid >> 2, cb = (tid & 3) * 8;
      const bf16* srcl = &Cs[row * 268 + cb];
      bf16* dst = Cp + (long long)(m0 + half * 128 + row) * Nll + n0 + cb;
#pragma unroll
      for (int j = 0; j < 8; ++j)
        *(bf16x8*)(dst + j * 32) = *(const bf16x8*)(srcl + j * 32);
      __syncthreads();
    }
  } else {
    float* Cs = (float*)smem;    // [64][268]
    float* Cp = (float*)Cout;
#pragma unroll
    for (int pass = 0; pass < 4; ++pass) {
      if (wm == (pass >> 1)) {
#pragma unroll
        for (int ni = 0; ni < 4; ++ni) {
          const int col = wn * 64 + ni * 16 + fr;
          const int gcol = n0 + col;
          float bb = 0.f;
          if (bias) bb = (bias2 && gcol >= 768) ? bias2[gcol - 768] : bias[gcol];
#pragma unroll
          for (int mi2 = 0; mi2 < 4; ++mi2) {
            const int mi = (pass & 1) * 4 + mi2;
#pragma unroll
            for (int r = 0; r < 4; ++r) {
              float v = acc[mi][ni][r] + bb;
              if (relu) v = fmaxf(v, 0.f);
              Cs[(mi2 * 16 + fq * 4 + r) * 268 + col] = v;
            }
          }
        }
      }
      __syncthreads();
      const int row = tid >> 3, c4 = (tid & 7) * 4;
      const float* srcl = &Cs[row * 268 + c4];
      float* dst = Cp + (long long)(m0 + pass * 64 + row) * Nll + n0 + c4;
#pragma unroll
      for (int j = 0; j < 8; ++j)
        *(float4*)(dst + j * 32) = *(const float4*)(srcl + j * 32);
      __syncthreads();
    }
  }
}

// ---------------------------------------------------------------------------
extern "C" void kernel_launch(void* const* d_in, const int* in_sizes, int n_in,
                              void* d_out, int out_size, void* d_ws, size_t ws_size,
                              hipStream_t stream) {
  (void)in_sizes; (void)n_in; (void)out_size; (void)ws_size;
  const float* x   = (const float*)d_in[0];
  const float* W1  = (const float*)d_in[1];
  const float* b1  = (const float*)d_in[2];
  const float* Wq  = (const float*)d_in[3];
  const float* bq  = (const float*)d_in[4];
  const float* Wk  = (const float*)d_in[5];
  const float* bk  = (const float*)d_in[6];
  const float* Wv  = (const float*)d_in[7];
  const float* bv  = (const float*)d_in[8];
  const float* Wo1 = (const float*)d_in[9];
  const float* bo1 = (const float*)d_in[10];
  const float* Wo2 = (const float*)d_in[11];
  const float* bo2 = (const float*)d_in[12];

  // workspace layout (bytes), slots reused across disjoint lifetimes
  char* ws = (char*)d_ws;
  bf16*  p    = (bf16*)(ws + 0);             // [25088,768]  then vt
  bf16*  vt   = (bf16*)(ws + 0);             // [128,768,224]
  bf16*  h    = (bf16*)(ws + 44040192LL);    // [25088,768]  then wv
  bf16*  wv   = (bf16*)(ws + 44040192LL);
  bf16*  kv   = (bf16*)(ws + 82575360LL);    // [25088,1536] then o1
  bf16*  o1   = (bf16*)(ws + 82575360LL);
  float* sc   = (float*)(ws + 159645696LL);  // [128,196,196] f32
  bf16*  q    = (bf16*)(ws + 179314688LL);   // [6272,768]   then attn
  bf16*  attn = (bf16*)(ws + 179314688LL);   // [128,196,224]
  bf16*  wt   = (bf16*)(ws + 190554112LL);   // 6 x 768x768
  constexpr long long WSZ = 768LL * 768;

  const float qk_scale = 0.03608439182435161f;   // 1/sqrt(768)

  patchify_k<<<4704, 256, 0, stream>>>(x, p);
  wtrans_k<<<dim3(24, 24, 6), 256, 0, stream>>>(W1, Wk, Wv, Wq, Wo1, Wo2, wt);

  // h = p @ W1 + b1                     [25088,768] bf16
  gemm256<<<dim3(3, 98), 512, 0, stream>>>(p, wt + 0 * WSZ, b1, nullptr, h,
      768, 768, 768, 768, 0, 1);
  // kv = h @ [Wk|Wv] + [bk|bv]          [25088,1536] bf16 (fused K,V)
  gemm256<<<dim3(6, 98), 512, 0, stream>>>(h, wt + 1 * WSZ, bk, bv, kv,
      1536, 768, 768, 768, 0, 1);
  // q = h[:,0] @ Wq + bq                [6272,768] bf16 (remap gr=196)
  gemm128<<<dim3(6, 49, 1), 256, 0, stream>>>(h, wt + 3 * WSZ, bq, nullptr, q,
      6272, 768, 768, 768, 768, 196, 602112LL, 0LL, 1, 0LL, 0LL, 1.f, 0, 1);
  // Vt[z][d][m], m padded to 224 (from kv cols 768..1535)
  vtrans_k<<<dim3(24, 7, 128), 256, 0, stream>>>(kv, vt);
  // scores[z][s][m] = (Q[b] K[z]^T) * scale   f32 (K rows inside kv, ldb=1536)
  gemm128<<<dim3(2, 2, 128), 256, 0, stream>>>(q, kv, nullptr, nullptr, sc,
      196, 196, 768, 768, 1536, 196, 0LL, 150528LL, 4, 301056LL, 38416LL,
      qk_scale, 0, 0);
  // attn = softmax(scores), bf16, K-padded to 224
  softmax_k<<<25088, 64, 0, stream>>>(sc, attn);
  // wv[z][s][d] = attn @ Vt   (K=224)
  gemm128<<<dim3(6, 2, 128), 256, 0, stream>>>(attn, vt, nullptr, nullptr, wv,
      196, 768, 224, 224, 224, 196, 0LL, 43904LL, 1, 172032LL, 150528LL,
      1.f, 0, 1);
  // o1 = relu(wv @ Wo1 + bo1)
  gemm256<<<dim3(3, 98), 512, 0, stream>>>(wv, wt + 4 * WSZ, bo1, nullptr, o1,
      768, 768, 768, 768, 1, 1);
  // out = o1 @ Wo2 + bo2   f32 -> d_out
  gemm256<<<dim3(3, 98), 512, 0, stream>>>(o1, wt + 5 * WSZ, bo2, nullptr,
      (float*)d_out, 768, 768, 768, 768, 0, 0);
}